// Round 1
// baseline (722.388 us; speedup 1.0000x reference)
//
#include <hip/hip_runtime.h>

#define UNITS 512
#define EMBD  256
#define BATCH 64
#define TLEN  2048

typedef __bf16 bf16x8 __attribute__((ext_vector_type(8)));
typedef float  f32x4  __attribute__((ext_vector_type(4)));

__device__ __forceinline__ unsigned short f2bf(float x) {
  return __builtin_bit_cast(unsigned short, (__bf16)x);
}
__device__ __forceinline__ float fast_tanh(float x) {
  float e = __expf(2.0f * x);
  return __fdividef(e - 1.0f, e + 1.0f);
}
__device__ __forceinline__ float fast_sigmoid(float x) {
  return __fdividef(1.0f, 1.0f + __expf(-x));
}

// ---------------------------------------------------------------------------
// K0: convert Wa (512x512 f32, [k][n]) into k-tiled transposed-ish bf16 layout
//     WaT[(ks*512 + n)*32 + kk]  (ks = k/32, kk = k%32), and zero gO/gL.
// ---------------------------------------------------------------------------
__global__ void prep_kernel(const float* __restrict__ Wa,
                            unsigned short* __restrict__ WaT,
                            float* __restrict__ gO, float* __restrict__ gL) {
  int idx = blockIdx.x * 256 + threadIdx.x;   // 0..262143, coalesced read of Wa
  int n = idx & 511;
  int k = idx >> 9;
  float v = Wa[idx];                          // Wa[k][n]
  int ks = k >> 5, kk = k & 31;
  WaT[(ks * 512 + n) * 32 + kk] = f2bf(v);
  if (idx < BATCH * UNITS) gO[idx] = 0.0f;
  if (idx < BATCH)         gL[idx] = 0.0f;
}

// ---------------------------------------------------------------------------
// Generic small GEMM: out[m][c] = dot(A[m][:K], B[:,c]) (+b1[c]) (+b2[c]),
// optionally A-row scaled by 1/denom[m].  grid = (N/256, M), block = 256.
// ---------------------------------------------------------------------------
__global__ void rowdot_kernel(const float* __restrict__ A, int lda,
                              const float* __restrict__ Bm, int ldb,
                              const float* __restrict__ b1,
                              const float* __restrict__ b2,
                              const float* __restrict__ denom,
                              float* __restrict__ out, int ldo, int K) {
  __shared__ float Asm[512];
  const int m = blockIdx.y;
  const int c = blockIdx.x * 256 + threadIdx.x;
  float sc = 1.0f;
  if (denom) sc = __fdividef(1.0f, denom[m]);
  for (int k = threadIdx.x; k < K; k += 256) Asm[k] = A[m * lda + k] * sc;
  __syncthreads();
  float acc = 0.0f;
#pragma unroll 8
  for (int k = 0; k < K; ++k)
    acc = fmaf(Asm[k], Bm[(size_t)k * ldb + c], acc);
  if (b1) acc += b1[c];
  if (b2) acc += b2[c];
  out[m * ldo + c] = acc;
}

// ---------------------------------------------------------------------------
// K3: fused attention-score + softmax partials + weighted context sum.
// One block = (batch b, t-chunk of 64 rows). Full N=512 accumulated in regs
// (f32x4 acc[4][8] = 128 VGPRs/lane). K-loop: 16 steps of BK=32.
//  s_t = sum_n tanh(Y[t][n] + u[b][n]) * Va[n]   (ba_v dropped: softmax-inv)
//  e_t = exp(s_t)  (bounded: |s| <= sum|Va| ~ 8, no max-sub needed)
//  gL[b] += sum_t e_t ;  gO[b][:] += sum_t e_t * ctx[t][:]
// ---------------------------------------------------------------------------
__launch_bounds__(256, 2)
__global__ void score_ctx_kernel(const float* __restrict__ ctx,
                                 const unsigned short* __restrict__ WaT,
                                 const float* __restrict__ uvec,
                                 const float* __restrict__ Va,
                                 float* __restrict__ gO,
                                 float* __restrict__ gL) {
  __shared__ unsigned short As[64][40];    // 64 t-rows x (32 k + 8 pad) bf16
  __shared__ unsigned short Bs[512][40];   // 512 n-rows x (32 k + 8 pad) bf16
  __shared__ float sS[64];
  __shared__ float sE[64];

  const int b   = blockIdx.y;
  const int tc  = blockIdx.x;
  const int tid = threadIdx.x;
  const int lane  = tid & 63;
  const int w     = tid >> 6;      // wave 0..3
  const int row_a = lane & 15;     // MFMA row/col-in-tile
  const int kq    = lane >> 4;     // MFMA k-quad

  const float* ctile = ctx + ((size_t)b * TLEN + (size_t)tc * 64) * UNITS;

  if (tid < 64) sS[tid] = 0.0f;

  f32x4 acc[4][8];
#pragma unroll
  for (int mt = 0; mt < 4; ++mt)
#pragma unroll
    for (int nt = 0; nt < 8; ++nt)
      acc[mt][nt] = (f32x4){0.0f, 0.0f, 0.0f, 0.0f};

  const int r_st = tid & 63;   // As staging: row
  const int half = tid >> 6;   // As staging: which 8-float slice

  for (int ks = 0; ks < 16; ++ks) {
    __syncthreads();
    // ---- stage A tile: ctx[64 x 32] f32 -> bf16 LDS (128B-aligned lines) ----
    {
      const float4* src = (const float4*)(ctile + r_st * UNITS + ks * 32 + half * 8);
      float4 v0 = src[0], v1 = src[1];
      ushort4 p0 = make_ushort4(f2bf(v0.x), f2bf(v0.y), f2bf(v0.z), f2bf(v0.w));
      ushort4 p1 = make_ushort4(f2bf(v1.x), f2bf(v1.y), f2bf(v1.z), f2bf(v1.w));
      *(ushort4*)&As[r_st][half * 8]     = p0;
      *(ushort4*)&As[r_st][half * 8 + 4] = p1;
    }
    // ---- stage B tile: WaT k-slab, 512 x 32 bf16 = 32KB, fully coalesced ----
    {
      const uint4* src = (const uint4*)(WaT + ks * 16384);
#pragma unroll
      for (int rep = 0; rep < 2; ++rep) {
        int n = rep * 256 + tid;
        const uint4* s4 = src + n * 4;
        uint4 a0 = s4[0], a1 = s4[1], a2 = s4[2], a3 = s4[3];
        uint4* dst = (uint4*)&Bs[n][0];
        dst[0] = a0; dst[1] = a1; dst[2] = a2; dst[3] = a3;
      }
    }
    __syncthreads();
    // ---- MFMA: 4 m-tiles x 8 n-tiles, K=32 ----
    bf16x8 af[4];
#pragma unroll
    for (int mt = 0; mt < 4; ++mt)
      af[mt] = *(const bf16x8*)&As[mt * 16 + row_a][kq * 8];
#pragma unroll
    for (int nt = 0; nt < 8; ++nt) {
      bf16x8 bf = *(const bf16x8*)&Bs[(w << 7) + (nt << 4) + row_a][kq * 8];
#pragma unroll
      for (int mt = 0; mt < 4; ++mt)
        acc[mt][nt] = __builtin_amdgcn_mfma_f32_16x16x32_bf16(af[mt], bf, acc[mt][nt], 0, 0, 0);
    }
  }

  // ---- epilogue: s_t = sum_n tanh(y + u) * Va ----
  float uvals[8], vvals[8];
#pragma unroll
  for (int nt = 0; nt < 8; ++nt) {
    int n_g = (w << 7) + (nt << 4) + row_a;
    uvals[nt] = uvec[b * UNITS + n_g];
    vvals[nt] = Va[n_g];
  }
#pragma unroll
  for (int mt = 0; mt < 4; ++mt) {
#pragma unroll
    for (int r = 0; r < 4; ++r) {
      float v = 0.0f;
#pragma unroll
      for (int nt = 0; nt < 8; ++nt)
        v += fast_tanh(acc[mt][nt][r] + uvals[nt]) * vvals[nt];
      v += __shfl_xor(v, 1);
      v += __shfl_xor(v, 2);
      v += __shfl_xor(v, 4);
      v += __shfl_xor(v, 8);
      if (row_a == 0) atomicAdd(&sS[mt * 16 + kq * 4 + r], v);
    }
  }
  __syncthreads();
  if (tid < 64) sE[tid] = __expf(sS[tid]);
  __syncthreads();
  if (tid < 64) {
    float e = sE[tid];
#pragma unroll
    for (int off = 1; off < 64; off <<= 1) e += __shfl_xor(e, off);
    if (tid == 0) atomicAdd(&gL[b], e);
  }
  // ---- weighted context accumulation (tile is L2-hot; coalesced re-read) ----
#pragma unroll
  for (int cc = 0; cc < 2; ++cc) {
    int c = cc * 256 + tid;
    float o = 0.0f;
#pragma unroll 8
    for (int t = 0; t < 64; ++t)
      o = fmaf(sE[t], ctile[t * UNITS + c], o);
    atomicAdd(&gO[b * UNITS + c], o);
  }
}

// ---------------------------------------------------------------------------
// gates: z,r and r*h
// ---------------------------------------------------------------------------
__global__ void gates_kernel(const float* __restrict__ xg,
                             const float* __restrict__ rec_zr,
                             const float* __restrict__ cg,
                             const float* __restrict__ h,
                             float* __restrict__ zbuf,
                             float* __restrict__ rhbuf) {
  int idx = blockIdx.x * 256 + threadIdx.x;   // 64*512
  int m = idx >> 9, j = idx & 511;
  float xz = xg[m * 1536 + j],        xr = xg[m * 1536 + 512 + j];
  float rz = rec_zr[m * 1024 + j],    rr = rec_zr[m * 1024 + 512 + j];
  float cz = cg[m * 1536 + j],        cr = cg[m * 1536 + 512 + j];
  float z = fast_sigmoid(xz + rz + cz);
  float r = fast_sigmoid(xr + rr + cr);
  zbuf[idx]  = z;
  rhbuf[idx] = r * h[idx];
}

// ---------------------------------------------------------------------------
// new h: h = z*h_tm1 + (1-z)*tanh(x_h + rec_h + c_h)
// ---------------------------------------------------------------------------
__global__ void newh_kernel(const float* __restrict__ xg,
                            const float* __restrict__ rech,
                            const float* __restrict__ cg,
                            const float* __restrict__ zbuf,
                            const float* __restrict__ h,
                            float* __restrict__ hout) {
  int idx = blockIdx.x * 256 + threadIdx.x;
  int m = idx >> 9, j = idx & 511;
  float hb = fast_tanh(xg[m * 1536 + 1024 + j] + rech[idx] + cg[m * 1536 + 1024 + j]);
  float z  = zbuf[idx];
  hout[idx] = z * h[idx] + (1.0f - z) * hb;
}

// ---------------------------------------------------------------------------
extern "C" void kernel_launch(void* const* d_in, const int* in_sizes, int n_in,
                              void* d_out, int out_size, void* d_ws, size_t ws_size,
                              hipStream_t stream) {
  (void)in_sizes; (void)n_in; (void)out_size; (void)ws_size;
  const float* inputs = (const float*)d_in[0];
  const float* h_tm1  = (const float*)d_in[1];
  const float* ctx    = (const float*)d_in[2];
  const float* Wi     = (const float*)d_in[3];
  const float* bi     = (const float*)d_in[4];
  const float* kern   = (const float*)d_in[5];
  const float* rk     = (const float*)d_in[6];
  const float* ak     = (const float*)d_in[7];
  const float* bias   = (const float*)d_in[8];
  const float* Wa     = (const float*)d_in[9];
  const float* ba_w   = (const float*)d_in[10];
  const float* Ua     = (const float*)d_in[11];
  const float* ba_u   = (const float*)d_in[12];
  const float* Va     = (const float*)d_in[13];
  // d_in[14] = ba_v: unused (softmax is shift-invariant)
  const float* Wo     = (const float*)d_in[15];
  const float* bo     = (const float*)d_in[16];

  float* out = (float*)d_out;               // [64][512] out, then [64][512] h
  float* ws  = (float*)d_ws;
  unsigned short* WaT = (unsigned short*)ws;    // 262144 bf16 = 131072 floats
  float* gO     = ws + 131072;   // [64][512]
  float* gL     = ws + 163840;   // [64]
  float* xbuf   = ws + 163904;   // [64][512]
  float* xg     = ws + 196672;   // [64][1536]
  float* ubuf   = ws + 294976;   // [64][512]
  float* rec_zr = ws + 327744;   // [64][1024]
  float* cg     = ws + 393280;   // [64][1536]
  float* zbuf   = ws + 491584;   // [64][512]
  float* rhbuf  = ws + 524352;   // [64][512]
  float* rech   = ws + 557120;   // [64][512]

  // K0: Wa -> bf16 tiled, zero accumulators
  prep_kernel<<<1024, 256, 0, stream>>>(Wa, WaT, gO, gL);
  // x = inputs @ Wi + bi
  rowdot_kernel<<<dim3(2, 64), 256, 0, stream>>>(inputs, EMBD, Wi, UNITS, bi, nullptr, nullptr, xbuf, UNITS, EMBD);
  // xg = x @ kernel + bias
  rowdot_kernel<<<dim3(6, 64), 256, 0, stream>>>(xbuf, UNITS, kern, 1536, bias, nullptr, nullptr, xg, 1536, UNITS);
  // u = h @ Ua + ba_u + ba_w
  rowdot_kernel<<<dim3(2, 64), 256, 0, stream>>>(h_tm1, UNITS, Ua, UNITS, ba_u, ba_w, nullptr, ubuf, UNITS, UNITS);
  // rec_z | rec_r = h @ RK[:, :1024]
  rowdot_kernel<<<dim3(4, 64), 256, 0, stream>>>(h_tm1, UNITS, rk, 1536, nullptr, nullptr, nullptr, rec_zr, 1024, UNITS);
  // fused attention
  score_ctx_kernel<<<dim3(32, 64), 256, 0, stream>>>(ctx, WaT, ubuf, Va, gO, gL);
  // cg = (gO/gL) @ attention_kernel
  rowdot_kernel<<<dim3(6, 64), 256, 0, stream>>>(gO, UNITS, ak, 1536, nullptr, nullptr, gL, cg, 1536, UNITS);
  // gates
  gates_kernel<<<128, 256, 0, stream>>>(xg, rec_zr, cg, h_tm1, zbuf, rhbuf);
  // rec_h = (r*h) @ RK[:, 1024:]
  rowdot_kernel<<<dim3(2, 64), 256, 0, stream>>>(rhbuf, UNITS, rk + 1024, 1536, nullptr, nullptr, nullptr, rech, UNITS, UNITS);
  // h
  newh_kernel<<<128, 256, 0, stream>>>(xg, rech, cg, zbuf, h_tm1, out + BATCH * UNITS);
  // out = h @ Wo + bo
  rowdot_kernel<<<dim3(2, 64), 256, 0, stream>>>(out + BATCH * UNITS, UNITS, Wo, UNITS, bo, nullptr, nullptr, out, UNITS, UNITS);
}

// Round 2
// 561.391 us; speedup vs baseline: 1.2868x; 1.2868x over previous
//
#include <hip/hip_runtime.h>

#define UNITS 512
#define EMBD  256
#define BATCH 64
#define TLEN  2048

typedef __bf16 bf16x8 __attribute__((ext_vector_type(8)));
typedef float  f32x4  __attribute__((ext_vector_type(4)));

__device__ __forceinline__ unsigned short f2bf(float x) {
  return __builtin_bit_cast(unsigned short, (__bf16)x);
}
__device__ __forceinline__ float fast_tanh(float x) {
  float e = __expf(2.0f * x);
  return __fdividef(e - 1.0f, e + 1.0f);
}
__device__ __forceinline__ float fast_sigmoid(float x) {
  return __fdividef(1.0f, 1.0f + __expf(-x));
}

// ---------------------------------------------------------------------------
// K0: re-lay Wa (512x512 f32, [k][n]) into exact MFMA B-fragment order:
//   WaF[((ks*32 + nt)*64 + lane)*8 + j] = bf16( Wa[ks*32 + (lane>>4)*8 + j]
//                                                 [nt*16 + (lane&15)] )
// so the score kernel loads B frags L2->reg with one 16B/lane coalesced load.
// Also zeros gO/gL accumulators.
// ---------------------------------------------------------------------------
__global__ void prep_kernel(const float* __restrict__ Wa,
                            unsigned short* __restrict__ WaF,
                            float* __restrict__ gO, float* __restrict__ gL) {
  int idx = blockIdx.x * 256 + threadIdx.x;   // 0..262143
  int j  = idx & 7;
  int l  = (idx >> 3) & 63;
  int nt = (idx >> 9) & 31;
  int ks = idx >> 14;
  int k = ks * 32 + ((l >> 4) << 3) + j;
  int n = (nt << 4) + (l & 15);
  WaF[idx] = f2bf(Wa[k * 512 + n]);
  if (idx < BATCH * UNITS) gO[idx] = 0.0f;
  if (idx < BATCH)         gL[idx] = 0.0f;
}

// ---------------------------------------------------------------------------
// Small GEMM, split-K: out[m][c] = dot(A[m][:K], B[:,c]) (+b1)(+b2), optional
// A-row scale 1/denom[m].  grid = (N/64, M), block = 256 = 64 cols x 4 ksegs.
// ---------------------------------------------------------------------------
__global__ void rowdot_kernel(const float* __restrict__ A, int lda,
                              const float* __restrict__ Bm, int ldb,
                              const float* __restrict__ b1,
                              const float* __restrict__ b2,
                              const float* __restrict__ denom,
                              float* __restrict__ out, int ldo, int K) {
  __shared__ float Asm[512];
  __shared__ float red[4][64];
  const int m  = blockIdx.y;
  const int cl = threadIdx.x & 63;
  const int ks = threadIdx.x >> 6;            // 0..3
  const int c  = (blockIdx.x << 6) + cl;
  float sc = 1.0f;
  if (denom) sc = __fdividef(1.0f, denom[m]);
  for (int k = threadIdx.x; k < K; k += 256) Asm[k] = A[m * lda + k] * sc;
  __syncthreads();
  const int kl = K >> 2;
  const float* bp = Bm + (size_t)(ks * kl) * ldb + c;
  float acc = 0.0f;
#pragma unroll 8
  for (int kk = 0; kk < kl; ++kk)
    acc = fmaf(Asm[ks * kl + kk], bp[(size_t)kk * ldb], acc);
  red[ks][cl] = acc;
  __syncthreads();
  if (threadIdx.x < 64) {
    int cc = (blockIdx.x << 6) + threadIdx.x;
    float v = red[0][threadIdx.x] + red[1][threadIdx.x] +
              red[2][threadIdx.x] + red[3][threadIdx.x];
    if (b1) v += b1[cc];
    if (b2) v += b2[cc];
    out[m * ldo + cc] = v;
  }
}

// ---------------------------------------------------------------------------
// K3: fused attention-score + softmax partials + weighted context sum.
// Block = (batch b, 64 t-rows). N=512 in regs (acc[4][8] f32x4 = 128 AGPR).
// Pipeline: A (ctx) prefetched 2 k-steps ahead in regs -> bf16 -> LDS dbuf;
// B (WaF) loaded L2->reg in frag order, 1 step ahead; one barrier per step.
// ---------------------------------------------------------------------------
__launch_bounds__(256, 2)
__global__ void score_ctx_kernel(const float* __restrict__ ctx,
                                 const unsigned short* __restrict__ WaF,
                                 const float* __restrict__ uvec,
                                 const float* __restrict__ Va,
                                 float* __restrict__ gO,
                                 float* __restrict__ gL) {
  __shared__ unsigned short As[2][64][40];   // 2 x (64 rows x 32k + 8 pad) bf16
  __shared__ float sS[64];
  __shared__ float sE[64];

  const int b   = blockIdx.y;
  const int tc  = blockIdx.x;
  const int tid = threadIdx.x;
  const int lane  = tid & 63;
  const int w     = tid >> 6;      // wave 0..3
  const int row_a = lane & 15;
  const int kq    = lane >> 4;

  const float* ctile = ctx + ((size_t)b * TLEN + (size_t)tc * 64) * UNITS;

  if (tid < 64) sS[tid] = 0.0f;

  f32x4 acc[4][8];
#pragma unroll
  for (int mt = 0; mt < 4; ++mt)
#pragma unroll
    for (int nt = 0; nt < 8; ++nt)
      acc[mt][nt] = (f32x4){0.0f, 0.0f, 0.0f, 0.0f};

  const int r_st = tid & 63;       // A staging row
  const int half = tid >> 6;       // which 8-float slice of the 32-k row

  const float4* abase = (const float4*)(ctile + r_st * UNITS + half * 8);
  // step ks slice for this thread: abase[ks*8], abase[ks*8+1]
  const bf16x8* bbase = (const bf16x8*)WaF + lane;

  float4 pa0[2], pa1[2];
  pa0[0] = abase[0]; pa0[1] = abase[1];        // A(0)
  pa1[0] = abase[8]; pa1[1] = abase[9];        // A(1)

  bf16x8 bcur[8], bnxt[8];
#pragma unroll
  for (int nt = 0; nt < 8; ++nt)
    bcur[nt] = bbase[(size_t)((w << 3) + nt) * 64];   // B(0)

  // stage A(0) into LDS buf 0
  {
    ushort4 q0 = make_ushort4(f2bf(pa0[0].x), f2bf(pa0[0].y), f2bf(pa0[0].z), f2bf(pa0[0].w));
    ushort4 q1 = make_ushort4(f2bf(pa0[1].x), f2bf(pa0[1].y), f2bf(pa0[1].z), f2bf(pa0[1].w));
    *(ushort4*)&As[0][r_st][half * 8]     = q0;
    *(ushort4*)&As[0][r_st][half * 8 + 4] = q1;
  }

#pragma unroll
  for (int ks = 0; ks < 16; ++ks) {
    const int cur = ks & 1;
    __syncthreads();                       // As[cur] visible; prev reads done
    // A fragments from LDS
    bf16x8 af[4];
#pragma unroll
    for (int mt = 0; mt < 4; ++mt)
      af[mt] = *(const bf16x8*)&As[cur][mt * 16 + row_a][kq * 8];
    // prefetch A(ks+2) into the now-free slot
    if (ks < 14) {
      float4* pdst = (cur == 0) ? pa0 : pa1;
      pdst[0] = abase[(ks + 2) * 8];
      pdst[1] = abase[(ks + 2) * 8 + 1];
    }
    // prefetch B(ks+1) straight from L2
    if (ks < 15) {
#pragma unroll
      for (int nt = 0; nt < 8; ++nt)
        bnxt[nt] = bbase[(size_t)((ks + 1) * 32 + (w << 3) + nt) * 64];
    }
    // MFMA: 4 m-tiles x 8 n-tiles
#pragma unroll
    for (int nt = 0; nt < 8; ++nt)
#pragma unroll
      for (int mt = 0; mt < 4; ++mt)
        acc[mt][nt] = __builtin_amdgcn_mfma_f32_16x16x32_bf16(af[mt], bcur[nt], acc[mt][nt], 0, 0, 0);
    // stage A(ks+1) (loaded 2 steps ago) into the other LDS buffer
    if (ks < 15) {
      const float4* psrc = (cur == 0) ? pa1 : pa0;
      ushort4 q0 = make_ushort4(f2bf(psrc[0].x), f2bf(psrc[0].y), f2bf(psrc[0].z), f2bf(psrc[0].w));
      ushort4 q1 = make_ushort4(f2bf(psrc[1].x), f2bf(psrc[1].y), f2bf(psrc[1].z), f2bf(psrc[1].w));
      *(ushort4*)&As[1 - cur][r_st][half * 8]     = q0;
      *(ushort4*)&As[1 - cur][r_st][half * 8 + 4] = q1;
#pragma unroll
      for (int nt = 0; nt < 8; ++nt) bcur[nt] = bnxt[nt];
    }
  }

  // ---- epilogue: s_t = sum_n tanh(y + u) * Va ----
  float uvals[8], vvals[8];
#pragma unroll
  for (int nt = 0; nt < 8; ++nt) {
    int n_g = (w << 7) + (nt << 4) + row_a;
    uvals[nt] = uvec[b * UNITS + n_g];
    vvals[nt] = Va[n_g];
  }
#pragma unroll
  for (int mt = 0; mt < 4; ++mt) {
#pragma unroll
    for (int r = 0; r < 4; ++r) {
      float v = 0.0f;
#pragma unroll
      for (int nt = 0; nt < 8; ++nt)
        v += fast_tanh(acc[mt][nt][r] + uvals[nt]) * vvals[nt];
      v += __shfl_xor(v, 1);
      v += __shfl_xor(v, 2);
      v += __shfl_xor(v, 4);
      v += __shfl_xor(v, 8);
      if (row_a == 0) atomicAdd(&sS[mt * 16 + kq * 4 + r], v);
    }
  }
  __syncthreads();
  if (tid < 64) sE[tid] = __expf(sS[tid]);
  __syncthreads();
  if (tid < 64) {
    float e = sE[tid];
#pragma unroll
    for (int off = 1; off < 64; off <<= 1) e += __shfl_xor(e, off);
    if (tid == 0) atomicAdd(&gL[b], e);
  }
  // ---- weighted context accumulation (tile L2/L3-hot; coalesced re-read) ----
#pragma unroll
  for (int cc = 0; cc < 2; ++cc) {
    int c = cc * 256 + tid;
    float o = 0.0f;
#pragma unroll 8
    for (int t = 0; t < 64; ++t)
      o = fmaf(sE[t], ctile[t * UNITS + c], o);
    atomicAdd(&gO[b * UNITS + c], o);
  }
}

// ---------------------------------------------------------------------------
// gates: z,r and r*h
// ---------------------------------------------------------------------------
__global__ void gates_kernel(const float* __restrict__ xg,
                             const float* __restrict__ rec_zr,
                             const float* __restrict__ cg,
                             const float* __restrict__ h,
                             float* __restrict__ zbuf,
                             float* __restrict__ rhbuf) {
  int idx = blockIdx.x * 256 + threadIdx.x;   // 64*512
  int m = idx >> 9, j = idx & 511;
  float xz = xg[m * 1536 + j],        xr = xg[m * 1536 + 512 + j];
  float rz = rec_zr[m * 1024 + j],    rr = rec_zr[m * 1024 + 512 + j];
  float cz = cg[m * 1536 + j],        cr = cg[m * 1536 + 512 + j];
  float z = fast_sigmoid(xz + rz + cz);
  float r = fast_sigmoid(xr + rr + cr);
  zbuf[idx]  = z;
  rhbuf[idx] = r * h[idx];
}

// ---------------------------------------------------------------------------
// new h: h = z*h_tm1 + (1-z)*tanh(x_h + rec_h + c_h)
// ---------------------------------------------------------------------------
__global__ void newh_kernel(const float* __restrict__ xg,
                            const float* __restrict__ rech,
                            const float* __restrict__ cg,
                            const float* __restrict__ zbuf,
                            const float* __restrict__ h,
                            float* __restrict__ hout) {
  int idx = blockIdx.x * 256 + threadIdx.x;
  int m = idx >> 9, j = idx & 511;
  float hb = fast_tanh(xg[m * 1536 + 1024 + j] + rech[idx] + cg[m * 1536 + 1024 + j]);
  float z  = zbuf[idx];
  hout[idx] = z * h[idx] + (1.0f - z) * hb;
}

// ---------------------------------------------------------------------------
extern "C" void kernel_launch(void* const* d_in, const int* in_sizes, int n_in,
                              void* d_out, int out_size, void* d_ws, size_t ws_size,
                              hipStream_t stream) {
  (void)in_sizes; (void)n_in; (void)out_size; (void)ws_size;
  const float* inputs = (const float*)d_in[0];
  const float* h_tm1  = (const float*)d_in[1];
  const float* ctx    = (const float*)d_in[2];
  const float* Wi     = (const float*)d_in[3];
  const float* bi     = (const float*)d_in[4];
  const float* kern   = (const float*)d_in[5];
  const float* rk     = (const float*)d_in[6];
  const float* ak     = (const float*)d_in[7];
  const float* bias   = (const float*)d_in[8];
  const float* Wa     = (const float*)d_in[9];
  const float* ba_w   = (const float*)d_in[10];
  const float* Ua     = (const float*)d_in[11];
  const float* ba_u   = (const float*)d_in[12];
  const float* Va     = (const float*)d_in[13];
  // d_in[14] = ba_v: unused (softmax is shift-invariant)
  const float* Wo     = (const float*)d_in[15];
  const float* bo     = (const float*)d_in[16];

  float* out = (float*)d_out;               // [64][512] out, then [64][512] h
  float* ws  = (float*)d_ws;
  unsigned short* WaF = (unsigned short*)ws;    // 262144 bf16
  float* gO     = ws + 131072;   // [64][512]
  float* gL     = ws + 163840;   // [64]
  float* xbuf   = ws + 163904;   // [64][512]
  float* xg     = ws + 196672;   // [64][1536]
  float* ubuf   = ws + 294976;   // [64][512]
  float* rec_zr = ws + 327744;   // [64][1024]
  float* cg     = ws + 393280;   // [64][1536]
  float* zbuf   = ws + 491584;   // [64][512]
  float* rhbuf  = ws + 524352;   // [64][512]
  float* rech   = ws + 557120;   // [64][512]

  // K0: Wa -> bf16 frag-order, zero accumulators
  prep_kernel<<<1024, 256, 0, stream>>>(Wa, WaF, gO, gL);
  // x = inputs @ Wi + bi
  rowdot_kernel<<<dim3(8, 64), 256, 0, stream>>>(inputs, EMBD, Wi, UNITS, bi, nullptr, nullptr, xbuf, UNITS, EMBD);
  // xg = x @ kernel + bias
  rowdot_kernel<<<dim3(24, 64), 256, 0, stream>>>(xbuf, UNITS, kern, 1536, bias, nullptr, nullptr, xg, 1536, UNITS);
  // u = h @ Ua + ba_u + ba_w
  rowdot_kernel<<<dim3(8, 64), 256, 0, stream>>>(h_tm1, UNITS, Ua, UNITS, ba_u, ba_w, nullptr, ubuf, UNITS, UNITS);
  // rec_z | rec_r = h @ RK[:, :1024]
  rowdot_kernel<<<dim3(16, 64), 256, 0, stream>>>(h_tm1, UNITS, rk, 1536, nullptr, nullptr, nullptr, rec_zr, 1024, UNITS);
  // fused attention
  score_ctx_kernel<<<dim3(32, 64), 256, 0, stream>>>(ctx, WaF, ubuf, Va, gO, gL);
  // cg = (gO/gL) @ attention_kernel
  rowdot_kernel<<<dim3(24, 64), 256, 0, stream>>>(gO, UNITS, ak, 1536, nullptr, nullptr, gL, cg, 1536, UNITS);
  // gates
  gates_kernel<<<128, 256, 0, stream>>>(xg, rec_zr, cg, h_tm1, zbuf, rhbuf);
  // rec_h = (r*h) @ RK[:, 1024:]
  rowdot_kernel<<<dim3(8, 64), 256, 0, stream>>>(rhbuf, UNITS, rk + 1024, 1536, nullptr, nullptr, nullptr, rech, UNITS, UNITS);
  // h
  newh_kernel<<<128, 256, 0, stream>>>(xg, rech, cg, zbuf, h_tm1, out + BATCH * UNITS);
  // out = h @ Wo + bo
  rowdot_kernel<<<dim3(8, 64), 256, 0, stream>>>(out + BATCH * UNITS, UNITS, Wo, UNITS, bo, nullptr, nullptr, out, UNITS, UNITS);
}